// Round 7
// baseline (212.801 us; speedup 1.0000x reference)
//
#include <hip/hip_runtime.h>
#include <hip/hip_fp16.h>
#include <cstdint>

// ---------------- workspace layout (bytes) ----------------
static constexpr size_t OFF_XT   = 0;                                   // fp16 xT [b][hw][c] packed u32 pairs, 16 MB
static constexpr size_t OFF_HIAL = 16777216;                            // f32 hi_al [b][c][hw] 32 MB
static constexpr size_t OFF_PART = OFF_HIAL;                            // ALIAS: part [18][b][32][4096] f32 (18.9 MB)
                                                                        // safe: k_meta consumes part before k_dcn writes hial
static constexpr size_t OFF_MW   = OFF_HIAL + 33554432;                 // float4 meta weights [b][9][4096]
static constexpr size_t OFF_MI   = OFF_MW  + 2ull*9*4096*16;            // int4 meta indices
static constexpr size_t OFF_WA   = OFF_MI  + 2ull*9*4096*16;            // fp16 wA [9][32oc][1024c] u32-packed (offconv)
static constexpr size_t OFF_WB   = OFF_WA  + 9ull*32*512*4;             // fp16 wB [32g][9p][32o][32i] u32-packed (dcn)
static constexpr size_t OFF_TMP  = OFF_WB  + 32ull*9*32*16*4;           // f32 tmp [b][1368][1024] (low-res conv of lo)
// end = OFF_TMP + 2*1368*1024*4 ~= 64.3 MB

using f16x8 = __attribute__((ext_vector_type(8))) _Float16;
typedef __attribute__((ext_vector_type(4))) float f32x4;

__device__ __forceinline__ uint16_t f2h(float f) { return __half_as_ushort(__float2half(f)); }
__device__ __forceinline__ __half2 u2h(uint32_t u) { union { uint32_t u; __half2 h; } x; x.u = u; return x.h; }
__device__ __forceinline__ uint32_t h2u(__half2 h) { union { uint32_t u; __half2 h; } x; x.h = h; return x.u; }

__device__ __forceinline__ f16x8 blend4(uint4 A, uint4 B, uint4 C, uint4 D, float4 wv) {
    __half2 h00 = __float2half2_rn(wv.x), h01 = __float2half2_rn(wv.y);
    __half2 h10 = __float2half2_rn(wv.z), h11 = __float2half2_rn(wv.w);
    const uint32_t* a = (const uint32_t*)&A;
    const uint32_t* b = (const uint32_t*)&B;
    const uint32_t* c = (const uint32_t*)&C;
    const uint32_t* d = (const uint32_t*)&D;
    union { uint32_t u[4]; f16x8 v; } r;
#pragma unroll
    for (int e = 0; e < 4; ++e) {
        __half2 acc = __hmul2(h00, u2h(a[e]));
        acc = __hfma2(h01, u2h(b[e]), acc);
        acc = __hfma2(h10, u2h(c[e]), acc);
        acc = __hfma2(h11, u2h(d[e]), acc);
        r.u[e] = h2u(acc);
    }
    return r.v;
}

// ---------------- prep: weight transposes ----------------
__global__ void k_prep_wa(const float* __restrict__ w_off, uint32_t* __restrict__ wa) {
    int idx = blockIdx.x * 256 + threadIdx.x;              // 9*32*512
    if (idx >= 9 * 32 * 512) return;
    int p = idx / (32 * 512), r = idx % (32 * 512), oc = r / 512, cp = r % 512;
    uint32_t lo = 0, hi = 0;
    if (oc < 27) {
        lo = f2h(w_off[(size_t)oc * 9216 + (size_t)(cp * 2) * 9 + p]);
        hi = f2h(w_off[(size_t)oc * 9216 + (size_t)(cp * 2 + 1) * 9 + p]);
    }
    wa[idx] = lo | (hi << 16);
}

__global__ void k_prep_wb(const float* __restrict__ w_dcn, uint32_t* __restrict__ wb) {
    int idx = blockIdx.x * 256 + threadIdx.x;              // 32*9*32*16
    if (idx >= 32 * 9 * 32 * 16) return;
    int g = idx / (9 * 32 * 16), r = idx % (9 * 32 * 16);
    int p = r / (32 * 16), r2 = r % (32 * 16), o = r2 / 16, ip = r2 % 16;
    uint32_t lo = f2h(w_dcn[((size_t)(g * 32 + o) * 32 + 2 * ip) * 9 + p]);
    uint32_t hi = f2h(w_dcn[((size_t)(g * 32 + o) * 32 + 2 * ip + 1) * 9 + p]);
    wb[idx] = lo | (hi << 16);
}

// ---------------- K0: hi_res NCHW f32 -> NHWC fp16 (packed pairs) ----------------
__global__ void k_transpose(const float* __restrict__ x, uint32_t* __restrict__ xt) {
    __shared__ float tile[64][65];
    int cblk = blockIdx.x * 64, y = blockIdx.y, b = blockIdx.z, t = threadIdx.x;
    const float* src = x + ((size_t)(b * 1024 + cblk)) * 4096 + y * 64;
#pragma unroll
    for (int k = 0; k < 16; ++k) {
        int lin = t + k * 256;
        int cl = lin >> 6, xx = lin & 63;
        tile[cl][xx] = src[(size_t)cl * 4096 + xx];
    }
    __syncthreads();
    uint32_t* dst = xt + ((size_t)b * 4096 + y * 64) * 512 + (cblk >> 1);
#pragma unroll
    for (int k = 0; k < 8; ++k) {
        int lin = t + k * 256;
        int xx = lin >> 5, cp = lin & 31;
        uint32_t lo = f2h(tile[2 * cp][xx]);
        uint32_t hi = f2h(tile[2 * cp + 1][xx]);
        dst[(size_t)xx * 512 + cp] = lo | (hi << 16);
    }
}

// ---------------- K1: offset conv via MFMA (fp16), 9 shifts x 2 K-halves ----------------
__global__ __launch_bounds__(256) void k_offconv_mfma(const uint32_t* __restrict__ xt,
                                                      const uint32_t* __restrict__ wa,
                                                      float* __restrict__ part) {
    int sp = blockIdx.x;                       // 0..17: shift p = sp>>1, K-half = sp&1
    int p = sp >> 1, kh = sp & 1;
    int y = blockIdx.y;
    int b = blockIdx.z;
    int t = threadIdx.x;
    int wave = t >> 6, lane = t & 63;
    int col = lane & 15, kg = lane >> 4;
    int x = wave * 16 + col;
    int ky = p / 3 - 1, kx = p % 3 - 1;
    int ys = y + ky, xs = x + kx;
    bool ok = (ys >= 0) && (ys < 64) && (xs >= 0) && (xs < 64);
    int ps = ok ? (ys * 64 + xs) : 0;

    const uint32_t* bp = xt + (size_t)b * 4096 * 512 + (size_t)ps * 512 + kh * 256 + kg * 4;
    const uint32_t* a0 = wa + ((size_t)p * 32 + col) * 512 + kh * 256 + kg * 4;
    const uint32_t* a1 = a0 + 16 * 512;

    f32x4 acc0 = {0.f, 0.f, 0.f, 0.f};
    f32x4 acc1 = {0.f, 0.f, 0.f, 0.f};
#pragma unroll 4
    for (int ks = 0; ks < 16; ++ks) {
        f16x8 bfrag = {0, 0, 0, 0, 0, 0, 0, 0};
        if (ok) bfrag = *(const f16x8*)(bp + ks * 16);
        f16x8 af0 = *(const f16x8*)(a0 + ks * 16);
        f16x8 af1 = *(const f16x8*)(a1 + ks * 16);
        acc0 = __builtin_amdgcn_mfma_f32_16x16x32_f16(af0, bfrag, acc0, 0, 0, 0);
        acc1 = __builtin_amdgcn_mfma_f32_16x16x32_f16(af1, bfrag, acc1, 0, 0, 0);
    }
    float* pc = part + ((size_t)(sp * 2 + b)) * 32 * 4096 + (size_t)y * 64 + wave * 16 + col;
#pragma unroll
    for (int j = 0; j < 4; ++j) {
        pc[(size_t)(kg * 4 + j) * 4096]      = acc0[j];
        pc[(size_t)(16 + kg * 4 + j) * 4096] = acc1[j];
    }
}

// ---------------- K2: reduce 18 partials -> sampling meta ----------------
__global__ void k_meta(const float* __restrict__ part, const float* __restrict__ b_off,
                       float4* __restrict__ mw, int4* __restrict__ mi) {
    int idx = blockIdx.x * 256 + threadIdx.x;              // 2*9*4096
    if (idx >= 2 * 9 * 4096) return;
    int b = idx / (9 * 4096), r = idx % (9 * 4096), p = r / 4096, hw = r % 4096;
    int h = hw >> 6, w = hw & 63;
    float sdy = b_off[p], sdx = b_off[p + 9], sm = b_off[p + 18];
#pragma unroll
    for (int s = 0; s < 18; ++s) {
        const float* pb = part + ((size_t)(s * 2 + b)) * 32 * 4096 + hw;
        sdy += pb[(size_t)p * 4096];
        sdx += pb[(size_t)(p + 9) * 4096];
        sm  += pb[(size_t)(p + 18) * 4096];
    }
    float m = 1.f / (1.f + expf(-sm));
    int ky = p / 3 - 1, kx = p % 3 - 1;
    float sy = (float)(h + ky) + sdy;
    float sx = (float)(w + kx) + sdx;
    float y0f = floorf(sy), x0f = floorf(sx);
    float wy = sy - y0f, wx = sx - x0f;
    int y0 = (int)fminf(fmaxf(y0f, -2.f), 64.f);
    int x0 = (int)fminf(fmaxf(x0f, -2.f), 64.f);
    bool vy0 = (y0 >= 0) && (y0 < 64), vy1 = (y0 + 1 >= 0) && (y0 + 1 < 64);
    bool vx0 = (x0 >= 0) && (x0 < 64), vx1 = (x0 + 1 >= 0) && (x0 + 1 < 64);
    float w00 = (1.f - wy) * (1.f - wx) * m * ((vy0 && vx0) ? 1.f : 0.f);
    float w01 = (1.f - wy) * wx         * m * ((vy0 && vx1) ? 1.f : 0.f);
    float w10 = wy * (1.f - wx)         * m * ((vy1 && vx0) ? 1.f : 0.f);
    float w11 = wy * wx                 * m * ((vy1 && vx1) ? 1.f : 0.f);
    int cy0 = min(max(y0, 0), 63),     cx0 = min(max(x0, 0), 63);
    int cy1 = min(max(y0 + 1, 0), 63), cx1 = min(max(x0 + 1, 0), 63);
    mw[idx] = float4{w00, w01, w10, w11};
    mi[idx] = int4{cy0 * 64 + cx0, cy0 * 64 + cx1, cy1 * 64 + cx0, cy1 * 64 + cx1};
}

// ---------------- K3: deformable sample + grouped conv, LDS-staged texture ----------------
__global__ __launch_bounds__(256, 2) void k_dcn_lds(const uint32_t* __restrict__ xt,
                                                    const uint32_t* __restrict__ wb,
                                                    const float4* __restrict__ mw,
                                                    const int4* __restrict__ mi,
                                                    const float* __restrict__ b_dcn,
                                                    float* __restrict__ hial) {
    __shared__ uint4 ldsq[5120];               // 20 rows * 64 px * 64 B = 80 KB
    int g = blockIdx.x, band = blockIdx.y, b = blockIdx.z;
    int y0 = band * 8;
    int band_lo = y0 - 6;
    if (band_lo < 0) band_lo = 0;
    if (band_lo > 44) band_lo = 44;
    int t = threadIdx.x;

    {
        const uint32_t* src = xt + ((size_t)b * 4096 + (size_t)band_lo * 64) * 512 + g * 16;
#pragma unroll 4
        for (int i = 0; i < 20; ++i) {
            int Q = i * 256 + t;
            int s = Q >> 2;
            int q = (Q & 3) ^ (s & 3);
            ldsq[Q] = *(const uint4*)(src + (size_t)s * 512 + q * 4);
        }
    }
    __syncthreads();
    const uint32_t* ldsb = (const uint32_t*)ldsq;

    int wave = t >> 6, lane = t & 63;
    int col = lane & 15, kg = lane >> 4;
    const uint32_t* xb = xt + (size_t)b * 4096 * 512 + g * 16 + kg * 4;
    const uint32_t* wg = wb + (size_t)g * 9 * 32 * 16 + col * 16 + kg * 4;
    const float4* mwb = mw + (size_t)b * 9 * 4096;
    const int4*   mib = mi + (size_t)b * 9 * 4096;
    const float*  bd  = b_dcn + g * 32;
    int blo64 = band_lo * 64;

#define GATHER(CP, U)                                                              \
    {                                                                              \
        int s_ = (CP) - blo64;                                                     \
        int sc_ = s_ < 0 ? 0 : (s_ > 1279 ? 1279 : s_);                            \
        U = *(const uint4*)(ldsb + sc_ * 16 + ((kg ^ (sc_ & 3)) << 2));            \
        if ((unsigned)s_ >= 1280u)                                                 \
            U = *(const uint4*)(xb + (size_t)(CP) * 512);                          \
    }

    for (int r = 0; r < 8; ++r) {
        int pix = (y0 + r) * 64 + wave * 16 + col;
        f32x4 acc0 = {0.f, 0.f, 0.f, 0.f};
        f32x4 acc1 = {0.f, 0.f, 0.f, 0.f};
#pragma unroll
        for (int p = 0; p < 9; ++p) {
            float4 wv = mwb[p * 4096 + pix];
            int4   iv = mib[p * 4096 + pix];
            uint4 u0, u1, u2, u3;
            GATHER(iv.x, u0)
            GATHER(iv.y, u1)
            GATHER(iv.z, u2)
            GATHER(iv.w, u3)
            f16x8 bfr = blend4(u0, u1, u2, u3, wv);
            const uint32_t* ap = wg + (size_t)p * 512;
            f16x8 af0 = *(const f16x8*)ap;
            f16x8 af1 = *(const f16x8*)(ap + 256);
            acc0 = __builtin_amdgcn_mfma_f32_16x16x32_f16(af0, bfr, acc0, 0, 0, 0);
            acc1 = __builtin_amdgcn_mfma_f32_16x16x32_f16(af1, bfr, acc1, 0, 0, 0);
        }
        float* pc = hial + ((size_t)b * 1024 + g * 32) * 4096 + pix;
#pragma unroll
        for (int j = 0; j < 4; ++j) {
            pc[(size_t)(kg * 4 + j) * 4096]      = acc0[j] + bd[kg * 4 + j];
            pc[(size_t)(16 + kg * 4 + j) * 4096] = acc1[j] + bd[16 + kg * 4 + j];
        }
    }
#undef GATHER
}

// ---------------- K4a: low-res grouped 1x1 conv of lo (conv commutes with upsample) ----------------
// tmp[b][oc][1024] = sum_{i: c=g*12+i < 2048} w_post[oc][i] * lo[b][c][px]   (oc = g*8+o, oc < 1368)
__global__ __launch_bounds__(256) void k_lowconv(const float* __restrict__ lo,
                                                 const float* __restrict__ wp,
                                                 float* __restrict__ tmp) {
    int oc = blockIdx.x, b = blockIdx.y, t = threadIdx.x;
    int g = oc >> 3;
    const float* wr = wp + (size_t)oc * 12;      // wp[g*96 + o*12] == wp[oc*12]
    int nlo = 2048 - g * 12; if (nlo > 12) nlo = 12;
    const float* lb = lo + ((size_t)b * 2048 + g * 12) * 1024;
    float* op = tmp + ((size_t)b * 1368 + oc) * 1024;
    float w[12];
#pragma unroll
    for (int i = 0; i < 12; ++i) w[i] = (i < nlo) ? wr[i] : 0.f;
#pragma unroll
    for (int k2 = 0; k2 < 4; ++k2) {
        int px = k2 * 256 + t;
        float s = 0.f;
#pragma unroll
        for (int i = 0; i < 12; ++i)
            if (i < nlo) s += w[i] * lb[(size_t)i * 1024 + px];
        op[px] = s;
    }
}

// ---------------- K4b: upsample(tmp) + hial grouped conv + bias -> out ----------------
// wave-uniform group; float4 along w. g<170: pure upsample; g==170: mixed; g>170: pure hial.
__global__ __launch_bounds__(256) void k_post3(const float* __restrict__ tmp,
                                               const float* __restrict__ hial,
                                               const float* __restrict__ wp,
                                               const float* __restrict__ bp,
                                               float* __restrict__ out) {
    int gq = blockIdx.x, hq = blockIdx.y, b = blockIdx.z;
    int t = threadIdx.x;
    int g = gq * 4 + (t >> 6);
    int lane = t & 63, w4 = lane & 15, hsub = lane >> 4;
    int k = hq * 4 + hsub;                       // output rows 2k, 2k+1
    int cm = 2 * w4 - 1 < 0 ? 0 : 2 * w4 - 1;
    int cp = 2 * w4 + 2 > 31 ? 31 : 2 * w4 + 2;
    float* ob = out + ((size_t)b * 2048 + (size_t)g * 8) * 4096 + (size_t)(2 * k) * 64 + w4 * 4;
    int cbase = g * 12;

#pragma unroll
    for (int hi = 0; hi < 2; ++hi) {
        int h = 2 * k + hi;
        int r0 = hi ? k : (k > 0 ? k - 1 : 0);
        int r1 = hi ? (k < 31 ? k + 1 : 31) : k;
        float ty = hi ? 0.25f : 0.75f;
        float om = 1.f - ty;
        float4 v[12];
        if (g >= 170) {
            int imin = (g == 170) ? 8 : 0;
            for (int i = imin; i < 12; ++i)
                v[i] = *(const float4*)(hial + ((size_t)b * 1024 + cbase + i - 2048) * 4096 + h * 64 + w4 * 4);
        }
#pragma unroll
        for (int o = 0; o < 8; ++o) {
            float bias = bp[g * 8 + o];
            float a0 = bias, a1 = bias, a2 = bias, a3 = bias;
            if (g <= 170) {
                const float* tp = tmp + ((size_t)b * 1368 + g * 8 + o) * 1024;
                const float* q0 = tp + r0 * 32;
                const float* q1 = tp + r1 * 32;
                float  e0a = q0[cm]; float2 pa = *(const float2*)(q0 + 2 * w4); float e3a = q0[cp];
                float  e0b = q1[cm]; float2 pb = *(const float2*)(q1 + 2 * w4); float e3b = q1[cp];
                float u0 = 0.25f * e0a + 0.75f * pa.x, u1 = 0.75f * pa.x + 0.25f * pa.y;
                float u2 = 0.25f * pa.x + 0.75f * pa.y, u3 = 0.75f * pa.y + 0.25f * e3a;
                float s0 = 0.25f * e0b + 0.75f * pb.x, s1 = 0.75f * pb.x + 0.25f * pb.y;
                float s2 = 0.25f * pb.x + 0.75f * pb.y, s3 = 0.75f * pb.y + 0.25f * e3b;
                a0 += om * u0 + ty * s0; a1 += om * u1 + ty * s1;
                a2 += om * u2 + ty * s2; a3 += om * u3 + ty * s3;
            }
            if (g >= 170) {
                const float4* wr = (const float4*)(wp + (size_t)g * 96 + o * 12);
#define ACC(W, I) { a0 += (W) * v[I].x; a1 += (W) * v[I].y; a2 += (W) * v[I].z; a3 += (W) * v[I].w; }
                if (g > 170) {
                    float4 wA = wr[0], wB = wr[1], wC = wr[2];
                    ACC(wA.x, 0) ACC(wA.y, 1) ACC(wA.z, 2) ACC(wA.w, 3)
                    ACC(wB.x, 4) ACC(wB.y, 5) ACC(wB.z, 6) ACC(wB.w, 7)
                    ACC(wC.x, 8) ACC(wC.y, 9) ACC(wC.z, 10) ACC(wC.w, 11)
                } else {
                    float4 wC = wr[2];
                    ACC(wC.x, 8) ACC(wC.y, 9) ACC(wC.z, 10) ACC(wC.w, 11)
                }
#undef ACC
            }
            *(float4*)(ob + (size_t)o * 4096 + hi * 64) = float4{a0, a1, a2, a3};
        }
    }
}

extern "C" void kernel_launch(void* const* d_in, const int* in_sizes, int n_in,
                              void* d_out, int out_size, void* d_ws, size_t ws_size,
                              hipStream_t stream) {
    const float* lo_res = (const float*)d_in[0];
    const float* hi_res = (const float*)d_in[1];
    const float* w_off  = (const float*)d_in[2];
    const float* b_off  = (const float*)d_in[3];
    const float* w_dcn  = (const float*)d_in[4];
    const float* b_dcn  = (const float*)d_in[5];
    const float* w_post = (const float*)d_in[6];
    const float* b_post = (const float*)d_in[7];
    float* out = (float*)d_out;
    char* ws = (char*)d_ws;

    uint32_t* xt  = (uint32_t*)(ws + OFF_XT);
    float* hial   = (float*)(ws + OFF_HIAL);
    float* part   = (float*)(ws + OFF_PART);     // aliases hial region (consumed before hial written)
    float4* mwp   = (float4*)(ws + OFF_MW);
    int4* mip     = (int4*)(ws + OFF_MI);
    uint32_t* wa  = (uint32_t*)(ws + OFF_WA);
    uint32_t* wbp = (uint32_t*)(ws + OFF_WB);
    float* tmp    = (float*)(ws + OFF_TMP);

    k_prep_wa<<<(9 * 32 * 512 + 255) / 256, 256, 0, stream>>>(w_off, wa);
    k_prep_wb<<<(32 * 9 * 32 * 16 + 255) / 256, 256, 0, stream>>>(w_dcn, wbp);
    k_transpose<<<dim3(16, 64, 2), 256, 0, stream>>>(hi_res, xt);
    k_lowconv<<<dim3(1368, 2), 256, 0, stream>>>(lo_res, w_post, tmp);
    k_offconv_mfma<<<dim3(18, 64, 2), 256, 0, stream>>>(xt, wa, part);
    k_meta<<<(2 * 9 * 4096 + 255) / 256, 256, 0, stream>>>(part, b_off, mwp, mip);
    k_dcn_lds<<<dim3(32, 8, 2), 256, 0, stream>>>(xt, wbp, mwp, mip, b_dcn, hial);
    k_post3<<<dim3(64, 8, 2), 256, 0, stream>>>(tmp, hial, w_post, b_post, out);
}

// Round 8
// 166.585 us; speedup vs baseline: 1.2774x; 1.2774x over previous
//
#include <hip/hip_runtime.h>
#include <hip/hip_fp16.h>
#include <cstdint>

// ---------------- workspace layout (bytes) ----------------
// xt2: fp16 chunked-NHWC texture [b][kc=8][4096 px][128 ch] = 16.78 MB
static constexpr size_t OFF_XT   = 0;
static constexpr size_t OFF_HIAL = 16777216;                            // f32 hi_al [b][c][hw] 32 MB
static constexpr size_t OFF_PART = OFF_HIAL;                            // ALIAS: part [18][b][32][4096] f32 (18.9 MB)
                                                                        // safe: k_meta consumes part before k_dcn writes hial
static constexpr size_t OFF_MW   = OFF_HIAL + 33554432;                 // float4 meta weights [b][9][4096]
static constexpr size_t OFF_MI   = OFF_MW  + 2ull*9*4096*16;            // int4 meta indices
static constexpr size_t OFF_WA   = OFF_MI  + 2ull*9*4096*16;            // fp16 waT [9][8kc][4ks][2mt][16col][4kg] uint4 granules (589,824 B)
static constexpr size_t OFF_WB   = OFF_WA  + 36864ull*16;               // fp16 wB [32g][9p][32o][32i] u32-packed (589,824 B)
// end ~= 52 MB

using f16x8 = __attribute__((ext_vector_type(8))) _Float16;
typedef __attribute__((ext_vector_type(4))) float f32x4;
typedef __attribute__((ext_vector_type(2))) float f32x2;

__device__ __forceinline__ uint16_t f2h(float f) { return __half_as_ushort(__float2half(f)); }
__device__ __forceinline__ __half2 u2h(uint32_t u) { union { uint32_t u; __half2 h; } x; x.u = u; return x.h; }
__device__ __forceinline__ uint32_t h2u(__half2 h) { union { uint32_t u; __half2 h; } x; x.h = h; return x.u; }

__device__ __forceinline__ f16x8 blend4(uint4 A, uint4 B, uint4 C, uint4 D, float4 wv) {
    __half2 h00 = __float2half2_rn(wv.x), h01 = __float2half2_rn(wv.y);
    __half2 h10 = __float2half2_rn(wv.z), h11 = __float2half2_rn(wv.w);
    const uint32_t* a = (const uint32_t*)&A;
    const uint32_t* b = (const uint32_t*)&B;
    const uint32_t* c = (const uint32_t*)&C;
    const uint32_t* d = (const uint32_t*)&D;
    union { uint32_t u[4]; f16x8 v; } r;
#pragma unroll
    for (int e = 0; e < 4; ++e) {
        __half2 acc = __hmul2(h00, u2h(a[e]));
        acc = __hfma2(h01, u2h(b[e]), acc);
        acc = __hfma2(h10, u2h(c[e]), acc);
        acc = __hfma2(h11, u2h(d[e]), acc);
        r.u[e] = h2u(acc);
    }
    return r.v;
}

// ---------------- prep: offconv weights waT[p][kc][ks][mt][col][kg] (16B granules) ----------------
__global__ void k_prep_wa(const float* __restrict__ w_off, uint4* __restrict__ waT) {
    int idx = blockIdx.x * 256 + threadIdx.x;              // 9*8*4*2*16*4 = 36864
    if (idx >= 36864) return;
    int kg = idx & 3, col = (idx >> 2) & 15, mt = (idx >> 6) & 1;
    int ks = (idx >> 7) & 3, kc = (idx >> 9) & 7, p = idx >> 12;
    int oc = mt * 16 + col;
    int chb = kc * 128 + ks * 32 + kg * 8;
    union { uint32_t u[4]; uint4 v; } r;
#pragma unroll
    for (int e = 0; e < 4; ++e) {
        uint32_t lo = 0, hi = 0;
        if (oc < 27) {
            lo = f2h(w_off[(size_t)oc * 9216 + (size_t)(chb + 2 * e) * 9 + p]);
            hi = f2h(w_off[(size_t)oc * 9216 + (size_t)(chb + 2 * e + 1) * 9 + p]);
        }
        r.u[e] = lo | (hi << 16);
    }
    waT[idx] = r.v;
}

// wb[g][p][o][i] fp16 packed: [32][9][32][16] u32 (dcn weights)
__global__ void k_prep_wb(const float* __restrict__ w_dcn, uint32_t* __restrict__ wb) {
    int idx = blockIdx.x * 256 + threadIdx.x;              // 32*9*32*16
    if (idx >= 32 * 9 * 32 * 16) return;
    int g = idx / (9 * 32 * 16), r = idx % (9 * 32 * 16);
    int p = r / (32 * 16), r2 = r % (32 * 16), o = r2 / 16, ip = r2 % 16;
    uint32_t lo = f2h(w_dcn[((size_t)(g * 32 + o) * 32 + 2 * ip) * 9 + p]);
    uint32_t hi = f2h(w_dcn[((size_t)(g * 32 + o) * 32 + 2 * ip + 1) * 9 + p]);
    wb[idx] = lo | (hi << 16);
}

// ---------------- K0: hi_res NCHW f32 -> chunked-NHWC fp16 xt2[b][kc][px][128ch] ----------------
__global__ void k_transpose(const float* __restrict__ x, uint32_t* __restrict__ xt) {
    __shared__ float tile[64][65];
    int cblk = blockIdx.x * 64, y = blockIdx.y, b = blockIdx.z, t = threadIdx.x;
    const float* src = x + ((size_t)(b * 1024 + cblk)) * 4096 + y * 64;
#pragma unroll
    for (int k = 0; k < 16; ++k) {
        int lin = t + k * 256;
        int cl = lin >> 6, xx = lin & 63;
        tile[cl][xx] = src[(size_t)cl * 4096 + xx];
    }
    __syncthreads();
    int kc = cblk >> 7, half = (cblk & 64) >> 1;           // u32 offset within 128-ch chunk
    uint32_t* dst = xt + ((size_t)(b * 8 + kc) * 4096 + (size_t)y * 64) * 64 + half;
#pragma unroll
    for (int k = 0; k < 8; ++k) {
        int lin = t + k * 256;
        int xx = lin >> 5, cp = lin & 31;
        uint32_t lo = f2h(tile[2 * cp][xx]);
        uint32_t hi = f2h(tile[2 * cp + 1][xx]);
        dst[(size_t)xx * 64 + cp] = lo | (hi << 16);
    }
}

// ---------------- K1: offset conv via MFMA + LDS-staged texture tile ----------------
// block = (y, xhalf, khalf, b): stage [3 rows][34 px][128 ch] per kc-chunk (zero-padded
// boundaries), 9 shifts read B-frags from LDS (XOR-swizzled granules), A-frags contiguous.
__global__ __launch_bounds__(256, 4) void k_offconv_mfma(const uint32_t* __restrict__ xt,
                                                         const uint4* __restrict__ waT,
                                                         float* __restrict__ part) {
    __shared__ uint4 sb[1632];                 // 102 slots * 16 granules = 25.5 KB
    int bx = blockIdx.x;                       // 0..127
    int y = bx >> 1, xh = bx & 1;
    int kh = blockIdx.y, b = blockIdx.z;
    int t = threadIdx.x, wave = t >> 6, lane = t & 63;
    int pxg = wave >> 1, mt = wave & 1;
    int col = lane & 15, kg = lane >> 4;

    f32x4 acc[9];
#pragma unroll
    for (int p = 0; p < 9; ++p) acc[p] = f32x4{0.f, 0.f, 0.f, 0.f};

    for (int kc4 = 0; kc4 < 4; ++kc4) {
        int kc = kh * 4 + kc4;
        const uint32_t* srcb = xt + ((size_t)(b * 8 + kc) * 4096) * 64;
        // stage 102 slots x 16 granules, zero-padding outside the image
#pragma unroll
        for (int i = 0; i < 7; ++i) {
            int idx = i * 256 + t;
            if (idx < 1632) {
                int s = idx >> 4, q = idx & 15;
                int r = s >= 68 ? 2 : (s >= 34 ? 1 : 0);
                int pxl = s - r * 34;
                int gy = y - 1 + r, gx = xh * 32 - 1 + pxl;
                uint4 val = uint4{0, 0, 0, 0};
                if (gy >= 0 && gy < 64 && gx >= 0 && gx < 64)
                    val = *(const uint4*)(srcb + ((size_t)(gy * 64 + gx)) * 64 + q * 4);
                sb[s * 16 + (q ^ (s & 15))] = val;
            }
        }
        __syncthreads();
#pragma unroll
        for (int p = 0; p < 9; ++p) {
            int ky = p / 3 - 1, kx = p % 3 - 1;
            int pxl = pxg * 16 + col + kx + 1;
            int s = (ky + 1) * 34 + pxl;
#pragma unroll
            for (int ks = 0; ks < 4; ++ks) {
                f16x8 bfr = *(const f16x8*)&sb[s * 16 + ((ks * 4 + kg) ^ (s & 15))];
                int gidx = ((((p * 8 + kc) * 4 + ks) * 2 + mt) * 16 + col) * 4 + kg;
                f16x8 afr = *(const f16x8*)&waT[gidx];
                acc[p] = __builtin_amdgcn_mfma_f32_16x16x32_f16(afr, bfr, acc[p], 0, 0, 0);
            }
        }
        __syncthreads();
    }
    int px = y * 64 + xh * 32 + pxg * 16 + col;
#pragma unroll
    for (int p = 0; p < 9; ++p) {
        float* pc = part + ((size_t)((kh * 9 + p) * 2 + b)) * 32 * 4096 + px;
#pragma unroll
        for (int j = 0; j < 4; ++j)
            pc[(size_t)(mt * 16 + kg * 4 + j) * 4096] = acc[p][j];
    }
}

// ---------------- K2: reduce 18 partials -> sampling meta ----------------
__global__ void k_meta(const float* __restrict__ part, const float* __restrict__ b_off,
                       float4* __restrict__ mw, int4* __restrict__ mi) {
    int idx = blockIdx.x * 256 + threadIdx.x;              // 2*9*4096
    if (idx >= 2 * 9 * 4096) return;
    int b = idx / (9 * 4096), r = idx % (9 * 4096), p = r / 4096, hw = r % 4096;
    int h = hw >> 6, w = hw & 63;
    float sdy = b_off[p], sdx = b_off[p + 9], sm = b_off[p + 18];
#pragma unroll
    for (int s = 0; s < 18; ++s) {
        const float* pb = part + ((size_t)(s * 2 + b)) * 32 * 4096 + hw;
        sdy += pb[(size_t)p * 4096];
        sdx += pb[(size_t)(p + 9) * 4096];
        sm  += pb[(size_t)(p + 18) * 4096];
    }
    float m = 1.f / (1.f + expf(-sm));
    int ky = p / 3 - 1, kx = p % 3 - 1;
    float sy = (float)(h + ky) + sdy;
    float sx = (float)(w + kx) + sdx;
    float y0f = floorf(sy), x0f = floorf(sx);
    float wy = sy - y0f, wx = sx - x0f;
    int y0 = (int)fminf(fmaxf(y0f, -2.f), 64.f);
    int x0 = (int)fminf(fmaxf(x0f, -2.f), 64.f);
    bool vy0 = (y0 >= 0) && (y0 < 64), vy1 = (y0 + 1 >= 0) && (y0 + 1 < 64);
    bool vx0 = (x0 >= 0) && (x0 < 64), vx1 = (x0 + 1 >= 0) && (x0 + 1 < 64);
    float w00 = (1.f - wy) * (1.f - wx) * m * ((vy0 && vx0) ? 1.f : 0.f);
    float w01 = (1.f - wy) * wx         * m * ((vy0 && vx1) ? 1.f : 0.f);
    float w10 = wy * (1.f - wx)         * m * ((vy1 && vx0) ? 1.f : 0.f);
    float w11 = wy * wx                 * m * ((vy1 && vx1) ? 1.f : 0.f);
    int cy0 = min(max(y0, 0), 63),     cx0 = min(max(x0, 0), 63);
    int cy1 = min(max(y0 + 1, 0), 63), cx1 = min(max(x0 + 1, 0), 63);
    mw[idx] = float4{w00, w01, w10, w11};
    mi[idx] = int4{cy0 * 64 + cx0, cy0 * 64 + cx1, cy1 * 64 + cx0, cy1 * 64 + cx1};
}

// ---------------- K3: deformable sample + grouped conv, LDS-staged texture ----------------
__global__ __launch_bounds__(256, 2) void k_dcn_lds(const uint32_t* __restrict__ xt,
                                                    const uint32_t* __restrict__ wb,
                                                    const float4* __restrict__ mw,
                                                    const int4* __restrict__ mi,
                                                    const float* __restrict__ b_dcn,
                                                    float* __restrict__ hial) {
    __shared__ uint4 ldsq[5120];               // 20 rows * 64 px * 64 B = 80 KB
    int g = blockIdx.x, band = blockIdx.y, b = blockIdx.z;
    int y0 = band * 8;
    int band_lo = y0 - 6;
    if (band_lo < 0) band_lo = 0;
    if (band_lo > 44) band_lo = 44;
    int t = threadIdx.x;

    {
        const uint32_t* src = xt + ((size_t)(b * 8 + (g >> 2)) * 4096 + (size_t)band_lo * 64) * 64 + (g & 3) * 16;
#pragma unroll 4
        for (int i = 0; i < 20; ++i) {
            int Q = i * 256 + t;
            int s = Q >> 2;
            int q = (Q & 3) ^ (s & 3);
            ldsq[Q] = *(const uint4*)(src + (size_t)s * 64 + q * 4);
        }
    }
    __syncthreads();
    const uint32_t* ldsb = (const uint32_t*)ldsq;

    int wave = t >> 6, lane = t & 63;
    int col = lane & 15, kg = lane >> 4;
    const uint32_t* xb = xt + ((size_t)(b * 8 + (g >> 2)) * 4096) * 64 + (g & 3) * 16 + kg * 4;
    const uint32_t* wg = wb + (size_t)g * 9 * 32 * 16 + col * 16 + kg * 4;
    const float4* mwb = mw + (size_t)b * 9 * 4096;
    const int4*   mib = mi + (size_t)b * 9 * 4096;
    const float*  bd  = b_dcn + g * 32;
    int blo64 = band_lo * 64;

#define GATHER(CP, U)                                                              \
    {                                                                              \
        int s_ = (CP) - blo64;                                                     \
        int sc_ = s_ < 0 ? 0 : (s_ > 1279 ? 1279 : s_);                            \
        U = *(const uint4*)(ldsb + sc_ * 16 + ((kg ^ (sc_ & 3)) << 2));            \
        if ((unsigned)s_ >= 1280u)                                                 \
            U = *(const uint4*)(xb + (size_t)(CP) * 64);                           \
    }

    for (int r = 0; r < 8; ++r) {
        int pix = (y0 + r) * 64 + wave * 16 + col;
        f32x4 acc0 = {0.f, 0.f, 0.f, 0.f};
        f32x4 acc1 = {0.f, 0.f, 0.f, 0.f};
#pragma unroll
        for (int p = 0; p < 9; ++p) {
            float4 wv = mwb[p * 4096 + pix];
            int4   iv = mib[p * 4096 + pix];
            uint4 u0, u1, u2, u3;
            GATHER(iv.x, u0)
            GATHER(iv.y, u1)
            GATHER(iv.z, u2)
            GATHER(iv.w, u3)
            f16x8 bfr = blend4(u0, u1, u2, u3, wv);
            const uint32_t* ap = wg + (size_t)p * 512;
            f16x8 af0 = *(const f16x8*)ap;
            f16x8 af1 = *(const f16x8*)(ap + 256);
            acc0 = __builtin_amdgcn_mfma_f32_16x16x32_f16(af0, bfr, acc0, 0, 0, 0);
            acc1 = __builtin_amdgcn_mfma_f32_16x16x32_f16(af1, bfr, acc1, 0, 0, 0);
        }
        float* pc = hial + ((size_t)b * 1024 + g * 32) * 4096 + pix;
#pragma unroll
        for (int j = 0; j < 4; ++j) {
            pc[(size_t)(kg * 4 + j) * 4096]      = acc0[j] + bd[kg * 4 + j];
            pc[(size_t)(16 + kg * 4 + j) * 4096] = acc1[j] + bd[16 + kg * 4 + j];
        }
    }
#undef GATHER
}

// ---------------- K4: fused bilinear 2x upsample + grouped 1x1 conv (float4-wide) ----------------
// thread = (g, lo-row k, 4 out cols): 12 inputs read ONCE -> 8 oc x 2 rows x float4.
__global__ __launch_bounds__(256) void k_post4(const float* __restrict__ lo,
                                               const float* __restrict__ hial,
                                               const float* __restrict__ wp,
                                               const float* __restrict__ bp,
                                               float* __restrict__ out) {
    int gq = blockIdx.x, kq = blockIdx.y, b = blockIdx.z;
    int t = threadIdx.x;
    int g = gq * 4 + (t >> 6);
    int lane = t & 63, k = kq * 4 + (lane >> 4), w4 = lane & 15;
    int rm = k > 0 ? k - 1 : 0, rp = k < 31 ? k + 1 : 31;
    int cm = w4 > 0 ? 2 * w4 - 1 : 0, cp = w4 < 15 ? 2 * w4 + 2 : 31;

    f32x4 acc0[8], acc1[8];
#pragma unroll
    for (int o = 0; o < 8; ++o) {
        float bv = bp[g * 8 + o];
        acc0[o] = f32x4{bv, bv, bv, bv};
        acc1[o] = acc0[o];
    }
    const float* wrow = wp + (size_t)g * 96;
    int cbase = g * 12;
#pragma unroll
    for (int i = 0; i < 12; ++i) {
        int c = cbase + i;
        f32x4 va, vb;
        if (c < 2048) {
            const float* lb = lo + ((size_t)(b * 2048 + c)) * 1024;
            float em = lb[rm * 32 + cm];
            f32x2 fm = *(const f32x2*)(lb + rm * 32 + 2 * w4);
            float e3m = lb[rm * 32 + cp];
            float ek = lb[k * 32 + cm];
            f32x2 fk = *(const f32x2*)(lb + k * 32 + 2 * w4);
            float e3k = lb[k * 32 + cp];
            float ep = lb[rp * 32 + cm];
            f32x2 fp_ = *(const f32x2*)(lb + rp * 32 + 2 * w4);
            float e3p = lb[rp * 32 + cp];
            f32x4 hm = {0.25f * em + 0.75f * fm.x, 0.75f * fm.x + 0.25f * fm.y,
                        0.25f * fm.x + 0.75f * fm.y, 0.75f * fm.y + 0.25f * e3m};
            f32x4 hk = {0.25f * ek + 0.75f * fk.x, 0.75f * fk.x + 0.25f * fk.y,
                        0.25f * fk.x + 0.75f * fk.y, 0.75f * fk.y + 0.25f * e3k};
            f32x4 hp = {0.25f * ep + 0.75f * fp_.x, 0.75f * fp_.x + 0.25f * fp_.y,
                        0.25f * fp_.x + 0.75f * fp_.y, 0.75f * fp_.y + 0.25f * e3p};
            va = 0.25f * hm + 0.75f * hk;
            vb = 0.75f * hk + 0.25f * hp;
        } else {
            const float* hb = hial + ((size_t)(b * 1024 + c - 2048)) * 4096 + (size_t)(2 * k) * 64 + 4 * w4;
            va = *(const f32x4*)hb;
            vb = *(const f32x4*)(hb + 64);
        }
#pragma unroll
        for (int o = 0; o < 8; ++o) {
            float w = wrow[o * 12 + i];
            acc0[o] += w * va;
            acc1[o] += w * vb;
        }
    }
    float* ob = out + ((size_t)(b * 2048 + g * 8)) * 4096 + (size_t)(2 * k) * 64 + 4 * w4;
#pragma unroll
    for (int o = 0; o < 8; ++o) {
        *(f32x4*)(ob + (size_t)o * 4096)      = acc0[o];
        *(f32x4*)(ob + (size_t)o * 4096 + 64) = acc1[o];
    }
}

extern "C" void kernel_launch(void* const* d_in, const int* in_sizes, int n_in,
                              void* d_out, int out_size, void* d_ws, size_t ws_size,
                              hipStream_t stream) {
    const float* lo_res = (const float*)d_in[0];
    const float* hi_res = (const float*)d_in[1];
    const float* w_off  = (const float*)d_in[2];
    const float* b_off  = (const float*)d_in[3];
    const float* w_dcn  = (const float*)d_in[4];
    const float* b_dcn  = (const float*)d_in[5];
    const float* w_post = (const float*)d_in[6];
    const float* b_post = (const float*)d_in[7];
    float* out = (float*)d_out;
    char* ws = (char*)d_ws;

    uint32_t* xt  = (uint32_t*)(ws + OFF_XT);
    float* hial   = (float*)(ws + OFF_HIAL);
    float* part   = (float*)(ws + OFF_PART);     // aliases hial region (consumed before hial written)
    float4* mwp   = (float4*)(ws + OFF_MW);
    int4* mip     = (int4*)(ws + OFF_MI);
    uint4* waT    = (uint4*)(ws + OFF_WA);
    uint32_t* wbp = (uint32_t*)(ws + OFF_WB);

    k_prep_wa<<<144, 256, 0, stream>>>(w_off, waT);
    k_prep_wb<<<(32 * 9 * 32 * 16 + 255) / 256, 256, 0, stream>>>(w_dcn, wbp);
    k_transpose<<<dim3(16, 64, 2), 256, 0, stream>>>(hi_res, xt);
    k_offconv_mfma<<<dim3(128, 2, 2), 256, 0, stream>>>(xt, waT, part);
    k_meta<<<(2 * 9 * 4096 + 255) / 256, 256, 0, stream>>>(part, b_off, mwp, mip);
    k_dcn_lds<<<dim3(32, 8, 2), 256, 0, stream>>>(xt, wbp, mwp, mip, b_dcn, hial);
    k_post4<<<dim3(64, 8, 2), 256, 0, stream>>>(lo_res, hial, w_post, b_post, out);
}

// Round 9
// 149.127 us; speedup vs baseline: 1.4270x; 1.1171x over previous
//
#include <hip/hip_runtime.h>
#include <hip/hip_fp16.h>
#include <cstdint>

// ---------------- workspace layout (bytes) ----------------
// xt2: fp16 chunked-NHWC texture [b][kc=8][4096 px][128 ch] = 16.78 MB
static constexpr size_t OFF_XT   = 0;
static constexpr size_t OFF_HIAL = 16777216;                            // f32 hi_al [b][c][hw] 32 MB
static constexpr size_t OFF_PART = OFF_HIAL;                            // ALIAS: part [18][b][32][4096] f32 (18.9 MB)
                                                                        // safe: k_meta consumes part before k_dcn writes hial
static constexpr size_t OFF_MW   = OFF_HIAL + 33554432;                 // float4 meta weights [b][9][4096]
static constexpr size_t OFF_MI   = OFF_MW  + 2ull*9*4096*16;            // int4 meta indices
static constexpr size_t OFF_WA   = OFF_MI  + 2ull*9*4096*16;            // fp16 waT [9][8kc][4ks][2mt][16col][4kg] uint4 granules
static constexpr size_t OFF_WB   = OFF_WA  + 36864ull*16;               // fp16 wB [32g][9p][32o][32i] u32-packed (dcn)
// end ~= 52 MB

using f16x8 = __attribute__((ext_vector_type(8))) _Float16;
typedef __attribute__((ext_vector_type(4))) float f32x4;
typedef __attribute__((ext_vector_type(2))) float f32x2;

__device__ __forceinline__ uint16_t f2h(float f) { return __half_as_ushort(__float2half(f)); }
__device__ __forceinline__ __half2 u2h(uint32_t u) { union { uint32_t u; __half2 h; } x; x.u = u; return x.h; }
__device__ __forceinline__ uint32_t h2u(__half2 h) { union { uint32_t u; __half2 h; } x; x.h = h; return x.u; }

__device__ __forceinline__ f16x8 blend4(uint4 A, uint4 B, uint4 C, uint4 D, float4 wv) {
    __half2 h00 = __float2half2_rn(wv.x), h01 = __float2half2_rn(wv.y);
    __half2 h10 = __float2half2_rn(wv.z), h11 = __float2half2_rn(wv.w);
    const uint32_t* a = (const uint32_t*)&A;
    const uint32_t* b = (const uint32_t*)&B;
    const uint32_t* c = (const uint32_t*)&C;
    const uint32_t* d = (const uint32_t*)&D;
    union { uint32_t u[4]; f16x8 v; } r;
#pragma unroll
    for (int e = 0; e < 4; ++e) {
        __half2 acc = __hmul2(h00, u2h(a[e]));
        acc = __hfma2(h01, u2h(b[e]), acc);
        acc = __hfma2(h10, u2h(c[e]), acc);
        acc = __hfma2(h11, u2h(d[e]), acc);
        r.u[e] = h2u(acc);
    }
    return r.v;
}

// ---------------- prep: offconv weights waT[p][kc][ks][mt][col][kg] (16B granules) ----------------
__global__ void k_prep_wa(const float* __restrict__ w_off, uint4* __restrict__ waT) {
    int idx = blockIdx.x * 256 + threadIdx.x;              // 9*8*4*2*16*4 = 36864
    if (idx >= 36864) return;
    int kg = idx & 3, col = (idx >> 2) & 15, mt = (idx >> 6) & 1;
    int ks = (idx >> 7) & 3, kc = (idx >> 9) & 7, p = idx >> 12;
    int oc = mt * 16 + col;
    int chb = kc * 128 + ks * 32 + kg * 8;
    union { uint32_t u[4]; uint4 v; } r;
#pragma unroll
    for (int e = 0; e < 4; ++e) {
        uint32_t lo = 0, hi = 0;
        if (oc < 27) {
            lo = f2h(w_off[(size_t)oc * 9216 + (size_t)(chb + 2 * e) * 9 + p]);
            hi = f2h(w_off[(size_t)oc * 9216 + (size_t)(chb + 2 * e + 1) * 9 + p]);
        }
        r.u[e] = lo | (hi << 16);
    }
    waT[idx] = r.v;
}

// wb[g][p][o][i] fp16 packed: [32][9][32][16] u32 (dcn weights)
__global__ void k_prep_wb(const float* __restrict__ w_dcn, uint32_t* __restrict__ wb) {
    int idx = blockIdx.x * 256 + threadIdx.x;              // 32*9*32*16
    if (idx >= 32 * 9 * 32 * 16) return;
    int g = idx / (9 * 32 * 16), r = idx % (9 * 32 * 16);
    int p = r / (32 * 16), r2 = r % (32 * 16), o = r2 / 16, ip = r2 % 16;
    uint32_t lo = f2h(w_dcn[((size_t)(g * 32 + o) * 32 + 2 * ip) * 9 + p]);
    uint32_t hi = f2h(w_dcn[((size_t)(g * 32 + o) * 32 + 2 * ip + 1) * 9 + p]);
    wb[idx] = lo | (hi << 16);
}

// ---------------- K0: hi_res NCHW f32 -> chunked-NHWC fp16 xt2[b][kc][px][128ch] ----------------
__global__ void k_transpose(const float* __restrict__ x, uint32_t* __restrict__ xt) {
    __shared__ float tile[64][65];
    int cblk = blockIdx.x * 64, y = blockIdx.y, b = blockIdx.z, t = threadIdx.x;
    const float* src = x + ((size_t)(b * 1024 + cblk)) * 4096 + y * 64;
#pragma unroll
    for (int k = 0; k < 16; ++k) {
        int lin = t + k * 256;
        int cl = lin >> 6, xx = lin & 63;
        tile[cl][xx] = src[(size_t)cl * 4096 + xx];
    }
    __syncthreads();
    int kc = cblk >> 7, half = (cblk & 64) >> 1;           // u32 offset within 128-ch chunk
    uint32_t* dst = xt + ((size_t)(b * 8 + kc) * 4096 + (size_t)y * 64) * 64 + half;
#pragma unroll
    for (int k = 0; k < 8; ++k) {
        int lin = t + k * 256;
        int xx = lin >> 5, cp = lin & 31;
        uint32_t lo = f2h(tile[2 * cp][xx]);
        uint32_t hi = f2h(tile[2 * cp + 1][xx]);
        dst[(size_t)xx * 64 + cp] = lo | (hi << 16);
    }
}

// ---------------- K1: offset conv via MFMA + LDS-staged texture tile ----------------
__global__ __launch_bounds__(256, 4) void k_offconv_mfma(const uint32_t* __restrict__ xt,
                                                         const uint4* __restrict__ waT,
                                                         float* __restrict__ part) {
    __shared__ uint4 sb[1632];                 // 102 slots * 16 granules = 25.5 KB
    int bx = blockIdx.x;                       // 0..127
    int y = bx >> 1, xh = bx & 1;
    int kh = blockIdx.y, b = blockIdx.z;
    int t = threadIdx.x, wave = t >> 6, lane = t & 63;
    int pxg = wave >> 1, mt = wave & 1;
    int col = lane & 15, kg = lane >> 4;

    f32x4 acc[9];
#pragma unroll
    for (int p = 0; p < 9; ++p) acc[p] = f32x4{0.f, 0.f, 0.f, 0.f};

    for (int kc4 = 0; kc4 < 4; ++kc4) {
        int kc = kh * 4 + kc4;
        const uint32_t* srcb = xt + ((size_t)(b * 8 + kc) * 4096) * 64;
#pragma unroll
        for (int i = 0; i < 7; ++i) {
            int idx = i * 256 + t;
            if (idx < 1632) {
                int s = idx >> 4, q = idx & 15;
                int r = s >= 68 ? 2 : (s >= 34 ? 1 : 0);
                int pxl = s - r * 34;
                int gy = y - 1 + r, gx = xh * 32 - 1 + pxl;
                uint4 val = uint4{0, 0, 0, 0};
                if (gy >= 0 && gy < 64 && gx >= 0 && gx < 64)
                    val = *(const uint4*)(srcb + ((size_t)(gy * 64 + gx)) * 64 + q * 4);
                sb[s * 16 + (q ^ (s & 15))] = val;
            }
        }
        __syncthreads();
#pragma unroll
        for (int p = 0; p < 9; ++p) {
            int ky = p / 3 - 1, kx = p % 3 - 1;
            int pxl = pxg * 16 + col + kx + 1;
            int s = (ky + 1) * 34 + pxl;
#pragma unroll
            for (int ks = 0; ks < 4; ++ks) {
                f16x8 bfr = *(const f16x8*)&sb[s * 16 + ((ks * 4 + kg) ^ (s & 15))];
                int gidx = ((((p * 8 + kc) * 4 + ks) * 2 + mt) * 16 + col) * 4 + kg;
                f16x8 afr = *(const f16x8*)&waT[gidx];
                acc[p] = __builtin_amdgcn_mfma_f32_16x16x32_f16(afr, bfr, acc[p], 0, 0, 0);
            }
        }
        __syncthreads();
    }
    int px = y * 64 + xh * 32 + pxg * 16 + col;
#pragma unroll
    for (int p = 0; p < 9; ++p) {
        float* pc = part + ((size_t)((kh * 9 + p) * 2 + b)) * 32 * 4096 + px;
#pragma unroll
        for (int j = 0; j < 4; ++j)
            pc[(size_t)(mt * 16 + kg * 4 + j) * 4096] = acc[p][j];
    }
}

// ---------------- K2: reduce 18 partials -> sampling meta ----------------
__global__ void k_meta(const float* __restrict__ part, const float* __restrict__ b_off,
                       float4* __restrict__ mw, int4* __restrict__ mi) {
    int idx = blockIdx.x * 256 + threadIdx.x;              // 2*9*4096
    if (idx >= 2 * 9 * 4096) return;
    int b = idx / (9 * 4096), r = idx % (9 * 4096), p = r / 4096, hw = r % 4096;
    int h = hw >> 6, w = hw & 63;
    float sdy = b_off[p], sdx = b_off[p + 9], sm = b_off[p + 18];
#pragma unroll
    for (int s = 0; s < 18; ++s) {
        const float* pb = part + ((size_t)(s * 2 + b)) * 32 * 4096 + hw;
        sdy += pb[(size_t)p * 4096];
        sdx += pb[(size_t)(p + 9) * 4096];
        sm  += pb[(size_t)(p + 18) * 4096];
    }
    float m = 1.f / (1.f + expf(-sm));
    int ky = p / 3 - 1, kx = p % 3 - 1;
    float sy = (float)(h + ky) + sdy;
    float sx = (float)(w + kx) + sdx;
    float y0f = floorf(sy), x0f = floorf(sx);
    float wy = sy - y0f, wx = sx - x0f;
    int y0 = (int)fminf(fmaxf(y0f, -2.f), 64.f);
    int x0 = (int)fminf(fmaxf(x0f, -2.f), 64.f);
    bool vy0 = (y0 >= 0) && (y0 < 64), vy1 = (y0 + 1 >= 0) && (y0 + 1 < 64);
    bool vx0 = (x0 >= 0) && (x0 < 64), vx1 = (x0 + 1 >= 0) && (x0 + 1 < 64);
    float w00 = (1.f - wy) * (1.f - wx) * m * ((vy0 && vx0) ? 1.f : 0.f);
    float w01 = (1.f - wy) * wx         * m * ((vy0 && vx1) ? 1.f : 0.f);
    float w10 = wy * (1.f - wx)         * m * ((vy1 && vx0) ? 1.f : 0.f);
    float w11 = wy * wx                 * m * ((vy1 && vx1) ? 1.f : 0.f);
    int cy0 = min(max(y0, 0), 63),     cx0 = min(max(x0, 0), 63);
    int cy1 = min(max(y0 + 1, 0), 63), cx1 = min(max(x0 + 1, 0), 63);
    mw[idx] = float4{w00, w01, w10, w11};
    mi[idx] = int4{cy0 * 64 + cx0, cy0 * 64 + cx1, cy1 * 64 + cx0, cy1 * 64 + cx1};
}

// ---------------- K3: deformable sample + grouped conv, LDS-staged texture ----------------
__global__ __launch_bounds__(256, 2) void k_dcn_lds(const uint32_t* __restrict__ xt,
                                                    const uint32_t* __restrict__ wb,
                                                    const float4* __restrict__ mw,
                                                    const int4* __restrict__ mi,
                                                    const float* __restrict__ b_dcn,
                                                    float* __restrict__ hial) {
    __shared__ uint4 ldsq[5120];               // 20 rows * 64 px * 64 B = 80 KB
    int g = blockIdx.x, band = blockIdx.y, b = blockIdx.z;
    int y0 = band * 8;
    int band_lo = y0 - 6;
    if (band_lo < 0) band_lo = 0;
    if (band_lo > 44) band_lo = 44;
    int t = threadIdx.x;

    {
        const uint32_t* src = xt + ((size_t)(b * 8 + (g >> 2)) * 4096 + (size_t)band_lo * 64) * 64 + (g & 3) * 16;
#pragma unroll 4
        for (int i = 0; i < 20; ++i) {
            int Q = i * 256 + t;
            int s = Q >> 2;
            int q = (Q & 3) ^ (s & 3);
            ldsq[Q] = *(const uint4*)(src + (size_t)s * 64 + q * 4);
        }
    }
    __syncthreads();
    const uint32_t* ldsb = (const uint32_t*)ldsq;

    int wave = t >> 6, lane = t & 63;
    int col = lane & 15, kg = lane >> 4;
    const uint32_t* xb = xt + ((size_t)(b * 8 + (g >> 2)) * 4096) * 64 + (g & 3) * 16 + kg * 4;
    const uint32_t* wg = wb + (size_t)g * 9 * 32 * 16 + col * 16 + kg * 4;
    const float4* mwb = mw + (size_t)b * 9 * 4096;
    const int4*   mib = mi + (size_t)b * 9 * 4096;
    const float*  bd  = b_dcn + g * 32;
    int blo64 = band_lo * 64;

#define GATHER(CP, U)                                                              \
    {                                                                              \
        int s_ = (CP) - blo64;                                                     \
        int sc_ = s_ < 0 ? 0 : (s_ > 1279 ? 1279 : s_);                            \
        U = *(const uint4*)(ldsb + sc_ * 16 + ((kg ^ (sc_ & 3)) << 2));            \
        if ((unsigned)s_ >= 1280u)                                                 \
            U = *(const uint4*)(xb + (size_t)(CP) * 64);                           \
    }

    for (int r = 0; r < 8; ++r) {
        int pix = (y0 + r) * 64 + wave * 16 + col;
        f32x4 acc0 = {0.f, 0.f, 0.f, 0.f};
        f32x4 acc1 = {0.f, 0.f, 0.f, 0.f};
#pragma unroll
        for (int p = 0; p < 9; ++p) {
            float4 wv = mwb[p * 4096 + pix];
            int4   iv = mib[p * 4096 + pix];
            uint4 u0, u1, u2, u3;
            GATHER(iv.x, u0)
            GATHER(iv.y, u1)
            GATHER(iv.z, u2)
            GATHER(iv.w, u3)
            f16x8 bfr = blend4(u0, u1, u2, u3, wv);
            const uint32_t* ap = wg + (size_t)p * 512;
            f16x8 af0 = *(const f16x8*)ap;
            f16x8 af1 = *(const f16x8*)(ap + 256);
            acc0 = __builtin_amdgcn_mfma_f32_16x16x32_f16(af0, bfr, acc0, 0, 0, 0);
            acc1 = __builtin_amdgcn_mfma_f32_16x16x32_f16(af1, bfr, acc1, 0, 0, 0);
        }
        float* pc = hial + ((size_t)b * 1024 + g * 32) * 4096 + pix;
#pragma unroll
        for (int j = 0; j < 4; ++j) {
            pc[(size_t)(kg * 4 + j) * 4096]      = acc0[j] + bd[kg * 4 + j];
            pc[(size_t)(16 + kg * 4 + j) * 4096] = acc1[j] + bd[16 + kg * 4 + j];
        }
    }
#undef GATHER
}

// ---------------- K4: fused upsample + grouped 1x1 conv, v2 ----------------
// One dword-aligned float4 load per (channel,row) + cndmask edge fixup; scalar weights
// via readfirstlane; VGPR capped for 4 waves/SIMD.
__global__ __launch_bounds__(256, 4) void k_post5(const float* __restrict__ lo,
                                                  const float* __restrict__ hial,
                                                  const float* __restrict__ wp,
                                                  const float* __restrict__ bp,
                                                  float* __restrict__ out) {
    int gq = blockIdx.x, kq = blockIdx.y, b = blockIdx.z;
    int t = threadIdx.x;
    int g = __builtin_amdgcn_readfirstlane(gq * 4 + (t >> 6));
    int lane = t & 63, k = kq * 4 + (lane >> 4), w4 = lane & 15;
    int rm = k > 0 ? k - 1 : 0, rp = k < 31 ? k + 1 : 31;
    int lc = 2 * w4 - 1; lc = lc < 0 ? 0 : (lc > 28 ? 28 : lc);
    bool is0 = (w4 == 0), is15 = (w4 == 15);

    f32x4 acc0[8], acc1[8];
#pragma unroll
    for (int o = 0; o < 8; ++o) {
        float bv = bp[g * 8 + o];
        acc0[o] = f32x4{bv, bv, bv, bv};
        acc1[o] = acc0[o];
    }
    const float* wrow = wp + (size_t)g * 96;
    int cbase = g * 12;

#define UPROW(LB, R, H)                                                            \
    {                                                                              \
        f32x4 q = *(const f32x4*)((LB) + (R) * 32 + lc);                           \
        float e0 = is15 ? q.y : q.x;                                               \
        float p0 = is0 ? q.x : (is15 ? q.z : q.y);                                 \
        float p1 = is0 ? q.y : (is15 ? q.w : q.z);                                 \
        float e3 = is0 ? q.z : q.w;                                                \
        H = f32x4{0.25f * e0 + 0.75f * p0, 0.75f * p0 + 0.25f * p1,                \
                  0.25f * p0 + 0.75f * p1, 0.75f * p1 + 0.25f * e3};               \
    }
#define LOCH(I)                                                                    \
    {                                                                              \
        const float* lb = lo + ((size_t)(b * 2048 + cbase + (I))) * 1024;          \
        f32x4 hm, hk, hp;                                                          \
        UPROW(lb, rm, hm) UPROW(lb, k, hk) UPROW(lb, rp, hp)                       \
        f32x4 va = 0.25f * hm + 0.75f * hk;                                        \
        f32x4 vb = 0.75f * hk + 0.25f * hp;                                        \
        _Pragma("unroll")                                                          \
        for (int o = 0; o < 8; ++o) {                                              \
            float w = wrow[o * 12 + (I)];                                          \
            acc0[o] += w * va;                                                     \
            acc1[o] += w * vb;                                                     \
        }                                                                          \
    }
#define HICH(I)                                                                    \
    {                                                                              \
        const float* hb = hial + ((size_t)(b * 1024 + cbase + (I) - 2048)) * 4096  \
                          + (size_t)(2 * k) * 64 + 4 * w4;                         \
        f32x4 va = *(const f32x4*)hb;                                              \
        f32x4 vb = *(const f32x4*)(hb + 64);                                       \
        _Pragma("unroll")                                                          \
        for (int o = 0; o < 8; ++o) {                                              \
            float w = wrow[o * 12 + (I)];                                          \
            acc0[o] += w * va;                                                     \
            acc1[o] += w * vb;                                                     \
        }                                                                          \
    }

    if (g <= 169) {
#pragma unroll 4
        for (int i = 0; i < 12; ++i) LOCH(i)
    } else if (g >= 171) {
#pragma unroll 4
        for (int i = 0; i < 12; ++i) HICH(i)
    } else {
#pragma unroll 4
        for (int i = 0; i < 8; ++i) LOCH(i)
#pragma unroll
        for (int i = 8; i < 12; ++i) HICH(i)
    }
#undef LOCH
#undef HICH
#undef UPROW

    float* ob = out + ((size_t)(b * 2048 + g * 8)) * 4096 + (size_t)(2 * k) * 64 + 4 * w4;
#pragma unroll
    for (int o = 0; o < 8; ++o) {
        *(f32x4*)(ob + (size_t)o * 4096)      = acc0[o];
        *(f32x4*)(ob + (size_t)o * 4096 + 64) = acc1[o];
    }
}

extern "C" void kernel_launch(void* const* d_in, const int* in_sizes, int n_in,
                              void* d_out, int out_size, void* d_ws, size_t ws_size,
                              hipStream_t stream) {
    const float* lo_res = (const float*)d_in[0];
    const float* hi_res = (const float*)d_in[1];
    const float* w_off  = (const float*)d_in[2];
    const float* b_off  = (const float*)d_in[3];
    const float* w_dcn  = (const float*)d_in[4];
    const float* b_dcn  = (const float*)d_in[5];
    const float* w_post = (const float*)d_in[6];
    const float* b_post = (const float*)d_in[7];
    float* out = (float*)d_out;
    char* ws = (char*)d_ws;

    uint32_t* xt  = (uint32_t*)(ws + OFF_XT);
    float* hial   = (float*)(ws + OFF_HIAL);
    float* part   = (float*)(ws + OFF_PART);     // aliases hial region (consumed before hial written)
    float4* mwp   = (float4*)(ws + OFF_MW);
    int4* mip     = (int4*)(ws + OFF_MI);
    uint4* waT    = (uint4*)(ws + OFF_WA);
    uint32_t* wbp = (uint32_t*)(ws + OFF_WB);

    k_prep_wa<<<144, 256, 0, stream>>>(w_off, waT);
    k_prep_wb<<<(32 * 9 * 32 * 16 + 255) / 256, 256, 0, stream>>>(w_dcn, wbp);
    k_transpose<<<dim3(16, 64, 2), 256, 0, stream>>>(hi_res, xt);
    k_offconv_mfma<<<dim3(128, 2, 2), 256, 0, stream>>>(xt, waT, part);
    k_meta<<<(2 * 9 * 4096 + 255) / 256, 256, 0, stream>>>(part, b_off, mwp, mip);
    k_dcn_lds<<<dim3(32, 8, 2), 256, 0, stream>>>(xt, wbp, mwp, mip, b_dcn, hial);
    k_post5<<<dim3(64, 8, 2), 256, 0, stream>>>(lo_res, hial, w_post, b_post, out);
}

// Round 10
// 143.342 us; speedup vs baseline: 1.4846x; 1.0404x over previous
//
#include <hip/hip_runtime.h>
#include <hip/hip_fp16.h>
#include <cstdint>

// ---------------- workspace layout (bytes) ----------------
// xt2: fp16 chunked-NHWC texture [b][kc=8][4096 px][128 ch] = 16.78 MB
static constexpr size_t OFF_XT   = 0;
static constexpr size_t OFF_HIAL = 16777216;                            // f32 hi_al [b][c][hw] 32 MB
static constexpr size_t OFF_PART = OFF_HIAL;                            // ALIAS: part [18][b][32][4096] f32 (18.9 MB)
                                                                        // safe: k_meta consumes part before k_dcn writes hial
static constexpr size_t OFF_MW   = OFF_HIAL + 33554432;                 // float4 meta weights [b][9][4096]
static constexpr size_t OFF_MI   = OFF_MW  + 2ull*9*4096*16;            // int4 meta indices
static constexpr size_t OFF_WA   = OFF_MI  + 2ull*9*4096*16;            // fp16 waT [9][8kc][4ks][2mt][16col][4kg] uint4 granules
static constexpr size_t OFF_WB   = OFF_WA  + 36864ull*16;               // fp16 wB [32g][9p][32o][32i] u32-packed (dcn)
// end ~= 52 MB

using f16x8 = __attribute__((ext_vector_type(8))) _Float16;
typedef __attribute__((ext_vector_type(4))) float f32x4;
typedef __attribute__((ext_vector_type(2))) float f32x2;

__device__ __forceinline__ uint16_t f2h(float f) { return __half_as_ushort(__float2half(f)); }
__device__ __forceinline__ __half2 u2h(uint32_t u) { union { uint32_t u; __half2 h; } x; x.u = u; return x.h; }
__device__ __forceinline__ uint32_t h2u(__half2 h) { union { uint32_t u; __half2 h; } x; x.h = h; return x.u; }

__device__ __forceinline__ f16x8 blend4(uint4 A, uint4 B, uint4 C, uint4 D, float4 wv) {
    __half2 h00 = __float2half2_rn(wv.x), h01 = __float2half2_rn(wv.y);
    __half2 h10 = __float2half2_rn(wv.z), h11 = __float2half2_rn(wv.w);
    const uint32_t* a = (const uint32_t*)&A;
    const uint32_t* b = (const uint32_t*)&B;
    const uint32_t* c = (const uint32_t*)&C;
    const uint32_t* d = (const uint32_t*)&D;
    union { uint32_t u[4]; f16x8 v; } r;
#pragma unroll
    for (int e = 0; e < 4; ++e) {
        __half2 acc = __hmul2(h00, u2h(a[e]));
        acc = __hfma2(h01, u2h(b[e]), acc);
        acc = __hfma2(h10, u2h(c[e]), acc);
        acc = __hfma2(h11, u2h(d[e]), acc);
        r.u[e] = h2u(acc);
    }
    return r.v;
}

// ---------------- prep: offconv weights waT[p][kc][ks][mt][col][kg] (16B granules) ----------------
__global__ void k_prep_wa(const float* __restrict__ w_off, uint4* __restrict__ waT) {
    int idx = blockIdx.x * 256 + threadIdx.x;              // 9*8*4*2*16*4 = 36864
    if (idx >= 36864) return;
    int kg = idx & 3, col = (idx >> 2) & 15, mt = (idx >> 6) & 1;
    int ks = (idx >> 7) & 3, kc = (idx >> 9) & 7, p = idx >> 12;
    int oc = mt * 16 + col;
    int chb = kc * 128 + ks * 32 + kg * 8;
    union { uint32_t u[4]; uint4 v; } r;
#pragma unroll
    for (int e = 0; e < 4; ++e) {
        uint32_t lo = 0, hi = 0;
        if (oc < 27) {
            lo = f2h(w_off[(size_t)oc * 9216 + (size_t)(chb + 2 * e) * 9 + p]);
            hi = f2h(w_off[(size_t)oc * 9216 + (size_t)(chb + 2 * e + 1) * 9 + p]);
        }
        r.u[e] = lo | (hi << 16);
    }
    waT[idx] = r.v;
}

// wb[g][p][o][i] fp16 packed: [32][9][32][16] u32 (dcn weights)
__global__ void k_prep_wb(const float* __restrict__ w_dcn, uint32_t* __restrict__ wb) {
    int idx = blockIdx.x * 256 + threadIdx.x;              // 32*9*32*16
    if (idx >= 32 * 9 * 32 * 16) return;
    int g = idx / (9 * 32 * 16), r = idx % (9 * 32 * 16);
    int p = r / (32 * 16), r2 = r % (32 * 16), o = r2 / 16, ip = r2 % 16;
    uint32_t lo = f2h(w_dcn[((size_t)(g * 32 + o) * 32 + 2 * ip) * 9 + p]);
    uint32_t hi = f2h(w_dcn[((size_t)(g * 32 + o) * 32 + 2 * ip + 1) * 9 + p]);
    wb[idx] = lo | (hi << 16);
}

// ---------------- K0: hi_res NCHW f32 -> chunked-NHWC fp16 xt2[b][kc][px][128ch] ----------------
__global__ void k_transpose(const float* __restrict__ x, uint32_t* __restrict__ xt) {
    __shared__ float tile[64][65];
    int cblk = blockIdx.x * 64, y = blockIdx.y, b = blockIdx.z, t = threadIdx.x;
    const float* src = x + ((size_t)(b * 1024 + cblk)) * 4096 + y * 64;
#pragma unroll
    for (int k = 0; k < 16; ++k) {
        int lin = t + k * 256;
        int cl = lin >> 6, xx = lin & 63;
        tile[cl][xx] = src[(size_t)cl * 4096 + xx];
    }
    __syncthreads();
    int kc = cblk >> 7, half = (cblk & 64) >> 1;           // u32 offset within 128-ch chunk
    uint32_t* dst = xt + ((size_t)(b * 8 + kc) * 4096 + (size_t)y * 64) * 64 + half;
#pragma unroll
    for (int k = 0; k < 8; ++k) {
        int lin = t + k * 256;
        int xx = lin >> 5, cp = lin & 31;
        uint32_t lo = f2h(tile[2 * cp][xx]);
        uint32_t hi = f2h(tile[2 * cp + 1][xx]);
        dst[(size_t)xx * 64 + cp] = lo | (hi << 16);
    }
}

// ---------------- K1: offset conv via MFMA + LDS-staged texture tile ----------------
__global__ __launch_bounds__(256, 4) void k_offconv_mfma(const uint32_t* __restrict__ xt,
                                                         const uint4* __restrict__ waT,
                                                         float* __restrict__ part) {
    __shared__ uint4 sb[1632];                 // 102 slots * 16 granules = 25.5 KB
    int bx = blockIdx.x;                       // 0..127
    int y = bx >> 1, xh = bx & 1;
    int kh = blockIdx.y, b = blockIdx.z;
    int t = threadIdx.x, wave = t >> 6, lane = t & 63;
    int pxg = wave >> 1, mt = wave & 1;
    int col = lane & 15, kg = lane >> 4;

    f32x4 acc[9];
#pragma unroll
    for (int p = 0; p < 9; ++p) acc[p] = f32x4{0.f, 0.f, 0.f, 0.f};

    for (int kc4 = 0; kc4 < 4; ++kc4) {
        int kc = kh * 4 + kc4;
        const uint32_t* srcb = xt + ((size_t)(b * 8 + kc) * 4096) * 64;
#pragma unroll
        for (int i = 0; i < 7; ++i) {
            int idx = i * 256 + t;
            if (idx < 1632) {
                int s = idx >> 4, q = idx & 15;
                int r = s >= 68 ? 2 : (s >= 34 ? 1 : 0);
                int pxl = s - r * 34;
                int gy = y - 1 + r, gx = xh * 32 - 1 + pxl;
                uint4 val = uint4{0, 0, 0, 0};
                if (gy >= 0 && gy < 64 && gx >= 0 && gx < 64)
                    val = *(const uint4*)(srcb + ((size_t)(gy * 64 + gx)) * 64 + q * 4);
                sb[s * 16 + (q ^ (s & 15))] = val;
            }
        }
        __syncthreads();
#pragma unroll
        for (int p = 0; p < 9; ++p) {
            int ky = p / 3 - 1, kx = p % 3 - 1;
            int pxl = pxg * 16 + col + kx + 1;
            int s = (ky + 1) * 34 + pxl;
#pragma unroll
            for (int ks = 0; ks < 4; ++ks) {
                f16x8 bfr = *(const f16x8*)&sb[s * 16 + ((ks * 4 + kg) ^ (s & 15))];
                int gidx = ((((p * 8 + kc) * 4 + ks) * 2 + mt) * 16 + col) * 4 + kg;
                f16x8 afr = *(const f16x8*)&waT[gidx];
                acc[p] = __builtin_amdgcn_mfma_f32_16x16x32_f16(afr, bfr, acc[p], 0, 0, 0);
            }
        }
        __syncthreads();
    }
    int px = y * 64 + xh * 32 + pxg * 16 + col;
#pragma unroll
    for (int p = 0; p < 9; ++p) {
        float* pc = part + ((size_t)((kh * 9 + p) * 2 + b)) * 32 * 4096 + px;
#pragma unroll
        for (int j = 0; j < 4; ++j)
            pc[(size_t)(mt * 16 + kg * 4 + j) * 4096] = acc[p][j];
    }
}

// ---------------- K2: reduce 18 partials -> sampling meta ----------------
__global__ void k_meta(const float* __restrict__ part, const float* __restrict__ b_off,
                       float4* __restrict__ mw, int4* __restrict__ mi) {
    int idx = blockIdx.x * 256 + threadIdx.x;              // 2*9*4096
    if (idx >= 2 * 9 * 4096) return;
    int b = idx / (9 * 4096), r = idx % (9 * 4096), p = r / 4096, hw = r % 4096;
    int h = hw >> 6, w = hw & 63;
    float sdy = b_off[p], sdx = b_off[p + 9], sm = b_off[p + 18];
#pragma unroll
    for (int s = 0; s < 18; ++s) {
        const float* pb = part + ((size_t)(s * 2 + b)) * 32 * 4096 + hw;
        sdy += pb[(size_t)p * 4096];
        sdx += pb[(size_t)(p + 9) * 4096];
        sm  += pb[(size_t)(p + 18) * 4096];
    }
    float m = 1.f / (1.f + expf(-sm));
    int ky = p / 3 - 1, kx = p % 3 - 1;
    float sy = (float)(h + ky) + sdy;
    float sx = (float)(w + kx) + sdx;
    float y0f = floorf(sy), x0f = floorf(sx);
    float wy = sy - y0f, wx = sx - x0f;
    int y0 = (int)fminf(fmaxf(y0f, -2.f), 64.f);
    int x0 = (int)fminf(fmaxf(x0f, -2.f), 64.f);
    bool vy0 = (y0 >= 0) && (y0 < 64), vy1 = (y0 + 1 >= 0) && (y0 + 1 < 64);
    bool vx0 = (x0 >= 0) && (x0 < 64), vx1 = (x0 + 1 >= 0) && (x0 + 1 < 64);
    float w00 = (1.f - wy) * (1.f - wx) * m * ((vy0 && vx0) ? 1.f : 0.f);
    float w01 = (1.f - wy) * wx         * m * ((vy0 && vx1) ? 1.f : 0.f);
    float w10 = wy * (1.f - wx)         * m * ((vy1 && vx0) ? 1.f : 0.f);
    float w11 = wy * wx                 * m * ((vy1 && vx1) ? 1.f : 0.f);
    int cy0 = min(max(y0, 0), 63),     cx0 = min(max(x0, 0), 63);
    int cy1 = min(max(y0 + 1, 0), 63), cx1 = min(max(x0 + 1, 0), 63);
    mw[idx] = float4{w00, w01, w10, w11};
    mi[idx] = int4{cy0 * 64 + cx0, cy0 * 64 + cx1, cy1 * 64 + cx0, cy1 * 64 + cx1};
}

// ---------------- K3: deformable sample + grouped conv, LDS-staged texture ----------------
// 512 threads share the 80 KB band tile (2 blocks/CU -> 16 waves/CU).
// Swizzle pos = kg ^ ((s>>1)&3): 16 consecutive slots cover all 8 bank-quads evenly
// (2 lanes/bank on ds_read_b128 = conflict-free minimum).
__global__ __launch_bounds__(512, 4) void k_dcn_lds(const uint32_t* __restrict__ xt,
                                                    const uint32_t* __restrict__ wb,
                                                    const float4* __restrict__ mw,
                                                    const int4* __restrict__ mi,
                                                    const float* __restrict__ b_dcn,
                                                    float* __restrict__ hial) {
    __shared__ uint4 ldsq[5120];               // 20 rows * 64 px * 64 B = 80 KB
    int g = blockIdx.x, band = blockIdx.y, b = blockIdx.z;
    int y0 = band * 8;
    int band_lo = y0 - 6;
    if (band_lo < 0) band_lo = 0;
    if (band_lo > 44) band_lo = 44;
    int t = threadIdx.x;

    {
        const uint32_t* src = xt + ((size_t)(b * 8 + (g >> 2)) * 4096 + (size_t)band_lo * 64) * 64 + (g & 3) * 16;
#pragma unroll
        for (int i = 0; i < 10; ++i) {
            int Q = i * 512 + t;
            int s = Q >> 2;
            int q = (Q & 3) ^ ((s >> 1) & 3);
            ldsq[Q] = *(const uint4*)(src + (size_t)s * 64 + q * 4);
        }
    }
    __syncthreads();
    const uint32_t* ldsb = (const uint32_t*)ldsq;

    int wave = t >> 6, lane = t & 63;
    int col = lane & 15, kg = lane >> 4;
    int strip = (wave & 3) * 16;               // x-strip of 16 px
    int rbase = (wave >> 2) * 4;               // rows rbase..rbase+3 of the band
    const uint32_t* xb = xt + ((size_t)(b * 8 + (g >> 2)) * 4096) * 64 + (g & 3) * 16 + kg * 4;
    const uint32_t* wg = wb + (size_t)g * 9 * 32 * 16 + col * 16 + kg * 4;
    const float4* mwb = mw + (size_t)b * 9 * 4096;
    const int4*   mib = mi + (size_t)b * 9 * 4096;
    const float*  bd  = b_dcn + g * 32;
    int blo64 = band_lo * 64;

#define GATHER(CP, U)                                                              \
    {                                                                              \
        int s_ = (CP) - blo64;                                                     \
        int sc_ = s_ < 0 ? 0 : (s_ > 1279 ? 1279 : s_);                            \
        U = *(const uint4*)(ldsb + sc_ * 16 + ((kg ^ ((sc_ >> 1) & 3)) << 2));     \
        if ((unsigned)s_ >= 1280u)                                                 \
            U = *(const uint4*)(xb + (size_t)(CP) * 64);                           \
    }

    for (int r = 0; r < 4; ++r) {
        int pix = (y0 + rbase + r) * 64 + strip + col;
        f32x4 acc0 = {0.f, 0.f, 0.f, 0.f};
        f32x4 acc1 = {0.f, 0.f, 0.f, 0.f};
#pragma unroll
        for (int p = 0; p < 9; ++p) {
            float4 wv = mwb[p * 4096 + pix];
            int4   iv = mib[p * 4096 + pix];
            uint4 u0, u1, u2, u3;
            GATHER(iv.x, u0)
            GATHER(iv.y, u1)
            GATHER(iv.z, u2)
            GATHER(iv.w, u3)
            f16x8 bfr = blend4(u0, u1, u2, u3, wv);
            const uint32_t* ap = wg + (size_t)p * 512;
            f16x8 af0 = *(const f16x8*)ap;
            f16x8 af1 = *(const f16x8*)(ap + 256);
            acc0 = __builtin_amdgcn_mfma_f32_16x16x32_f16(af0, bfr, acc0, 0, 0, 0);
            acc1 = __builtin_amdgcn_mfma_f32_16x16x32_f16(af1, bfr, acc1, 0, 0, 0);
        }
        float* pc = hial + ((size_t)b * 1024 + g * 32) * 4096 + pix;
#pragma unroll
        for (int j = 0; j < 4; ++j) {
            pc[(size_t)(kg * 4 + j) * 4096]      = acc0[j] + bd[kg * 4 + j];
            pc[(size_t)(16 + kg * 4 + j) * 4096] = acc1[j] + bd[16 + kg * 4 + j];
        }
    }
#undef GATHER
}

// ---------------- K4: fused upsample + grouped 1x1 conv, v2 ----------------
__global__ __launch_bounds__(256, 4) void k_post5(const float* __restrict__ lo,
                                                  const float* __restrict__ hial,
                                                  const float* __restrict__ wp,
                                                  const float* __restrict__ bp,
                                                  float* __restrict__ out) {
    int gq = blockIdx.x, kq = blockIdx.y, b = blockIdx.z;
    int t = threadIdx.x;
    int g = __builtin_amdgcn_readfirstlane(gq * 4 + (t >> 6));
    int lane = t & 63, k = kq * 4 + (lane >> 4), w4 = lane & 15;
    int rm = k > 0 ? k - 1 : 0, rp = k < 31 ? k + 1 : 31;
    int lc = 2 * w4 - 1; lc = lc < 0 ? 0 : (lc > 28 ? 28 : lc);
    bool is0 = (w4 == 0), is15 = (w4 == 15);

    f32x4 acc0[8], acc1[8];
#pragma unroll
    for (int o = 0; o < 8; ++o) {
        float bv = bp[g * 8 + o];
        acc0[o] = f32x4{bv, bv, bv, bv};
        acc1[o] = acc0[o];
    }
    const float* wrow = wp + (size_t)g * 96;
    int cbase = g * 12;

#define UPROW(LB, R, H)                                                            \
    {                                                                              \
        f32x4 q = *(const f32x4*)((LB) + (R) * 32 + lc);                           \
        float e0 = is15 ? q.y : q.x;                                               \
        float p0 = is0 ? q.x : (is15 ? q.z : q.y);                                 \
        float p1 = is0 ? q.y : (is15 ? q.w : q.z);                                 \
        float e3 = is0 ? q.z : q.w;                                                \
        H = f32x4{0.25f * e0 + 0.75f * p0, 0.75f * p0 + 0.25f * p1,                \
                  0.25f * p0 + 0.75f * p1, 0.75f * p1 + 0.25f * e3};               \
    }
#define LOCH(I)                                                                    \
    {                                                                              \
        const float* lb = lo + ((size_t)(b * 2048 + cbase + (I))) * 1024;          \
        f32x4 hm, hk, hp;                                                          \
        UPROW(lb, rm, hm) UPROW(lb, k, hk) UPROW(lb, rp, hp)                       \
        f32x4 va = 0.25f * hm + 0.75f * hk;                                        \
        f32x4 vb = 0.75f * hk + 0.25f * hp;                                        \
        _Pragma("unroll")                                                          \
        for (int o = 0; o < 8; ++o) {                                              \
            float w = wrow[o * 12 + (I)];                                          \
            acc0[o] += w * va;                                                     \
            acc1[o] += w * vb;                                                     \
        }                                                                          \
    }
#define HICH(I)                                                                    \
    {                                                                              \
        const float* hb = hial + ((size_t)(b * 1024 + cbase + (I) - 2048)) * 4096  \
                          + (size_t)(2 * k) * 64 + 4 * w4;                         \
        f32x4 va = *(const f32x4*)hb;                                              \
        f32x4 vb = *(const f32x4*)(hb + 64);                                       \
        _Pragma("unroll")                                                          \
        for (int o = 0; o < 8; ++o) {                                              \
            float w = wrow[o * 12 + (I)];                                          \
            acc0[o] += w * va;                                                     \
            acc1[o] += w * vb;                                                     \
        }                                                                          \
    }

    if (g <= 169) {
#pragma unroll 4
        for (int i = 0; i < 12; ++i) LOCH(i)
    } else if (g >= 171) {
#pragma unroll 4
        for (int i = 0; i < 12; ++i) HICH(i)
    } else {
#pragma unroll 4
        for (int i = 0; i < 8; ++i) LOCH(i)
#pragma unroll
        for (int i = 8; i < 12; ++i) HICH(i)
    }
#undef LOCH
#undef HICH
#undef UPROW

    float* ob = out + ((size_t)(b * 2048 + g * 8)) * 4096 + (size_t)(2 * k) * 64 + 4 * w4;
#pragma unroll
    for (int o = 0; o < 8; ++o) {
        *(f32x4*)(ob + (size_t)o * 4096)      = acc0[o];
        *(f32x4*)(ob + (size_t)o * 4096 + 64) = acc1[o];
    }
}

extern "C" void kernel_launch(void* const* d_in, const int* in_sizes, int n_in,
                              void* d_out, int out_size, void* d_ws, size_t ws_size,
                              hipStream_t stream) {
    const float* lo_res = (const float*)d_in[0];
    const float* hi_res = (const float*)d_in[1];
    const float* w_off  = (const float*)d_in[2];
    const float* b_off  = (const float*)d_in[3];
    const float* w_dcn  = (const float*)d_in[4];
    const float* b_dcn  = (const float*)d_in[5];
    const float* w_post = (const float*)d_in[6];
    const float* b_post = (const float*)d_in[7];
    float* out = (float*)d_out;
    char* ws = (char*)d_ws;

    uint32_t* xt  = (uint32_t*)(ws + OFF_XT);
    float* hial   = (float*)(ws + OFF_HIAL);
    float* part   = (float*)(ws + OFF_PART);     // aliases hial region (consumed before hial written)
    float4* mwp   = (float4*)(ws + OFF_MW);
    int4* mip     = (int4*)(ws + OFF_MI);
    uint4* waT    = (uint4*)(ws + OFF_WA);
    uint32_t* wbp = (uint32_t*)(ws + OFF_WB);

    k_prep_wa<<<144, 256, 0, stream>>>(w_off, waT);
    k_prep_wb<<<(32 * 9 * 32 * 16 + 255) / 256, 256, 0, stream>>>(w_dcn, wbp);
    k_transpose<<<dim3(16, 64, 2), 256, 0, stream>>>(hi_res, xt);
    k_offconv_mfma<<<dim3(128, 2, 2), 256, 0, stream>>>(xt, waT, part);
    k_meta<<<(2 * 9 * 4096 + 255) / 256, 256, 0, stream>>>(part, b_off, mwp, mip);
    k_dcn_lds<<<dim3(32, 8, 2), 512, 0, stream>>>(xt, wbp, mwp, mip, b_dcn, hial);
    k_post5<<<dim3(64, 8, 2), 256, 0, stream>>>(lo_res, hial, w_post, b_post, out);
}